// Round 4
// baseline (189.585 us; speedup 1.0000x reference)
//
#include <hip/hip_runtime.h>
#include <cstddef>

typedef float f32x4 __attribute__((ext_vector_type(4)));
typedef short s16x4 __attribute__((ext_vector_type(4)));
typedef short s16x8 __attribute__((ext_vector_type(8)));
typedef __bf16 bf16x8 __attribute__((ext_vector_type(8)));

#define NB 8
#define NS 1024
#define ND 768
#define NH 12
#define HD 64

__device__ __forceinline__ unsigned short f2bf(float f) {
  unsigned u = __builtin_bit_cast(unsigned, f);
  u += 0x7fffu + ((u >> 16) & 1u);
  return (unsigned short)(u >> 16);
}

__device__ __forceinline__ f32x4 mfma16(bf16x8 a, bf16x8 b, f32x4 c) {
  return __builtin_amdgcn_mfma_f32_16x16x32_bf16(a, b, c, 0, 0, 0);
}

__device__ __forceinline__ bf16x8 ld8(const unsigned short* p) {
  return *reinterpret_cast<const bf16x8*>(p);
}

// async global->LDS, 16B per lane, wave-uniform LDS base + lane*16 (m97 pattern)
__device__ __forceinline__ void gload16(unsigned short* lds_dst, const unsigned short* gsrc) {
  __builtin_amdgcn_global_load_lds(
      (const __attribute__((address_space(1))) unsigned int*)gsrc,
      (__attribute__((address_space(3))) unsigned int*)lds_dst, 16, 0, 0);
}

// ---------------- pack kernels ----------------

__global__ __launch_bounds__(256) void cvt_f32_bf16(const float* __restrict__ in,
                                                    unsigned short* __restrict__ out) {
  int i = (blockIdx.x * 256 + threadIdx.x) * 4;
  float4 v = *reinterpret_cast<const float4*>(in + i);
  ushort4 o;
  o.x = f2bf(v.x); o.y = f2bf(v.y); o.z = f2bf(v.z); o.w = f2bf(v.w);
  *reinterpret_cast<ushort4*>(out + i) = o;
}

// in: fp32 [R][C] row-major  ->  out: bf16 [C][R]
__global__ __launch_bounds__(256) void transpose_cvt(const float* __restrict__ in,
                                                     unsigned short* __restrict__ out,
                                                     int R, int C) {
  __shared__ float tile[32][33];
  int c0 = blockIdx.x * 32, r0 = blockIdx.y * 32;
  int tx = threadIdx.x & 31, ty = threadIdx.x >> 5;  // 32 x 8
#pragma unroll
  for (int i = 0; i < 32; i += 8)
    tile[ty + i][tx] = in[(size_t)(r0 + ty + i) * C + c0 + tx];
  __syncthreads();
#pragma unroll
  for (int i = 0; i < 32; i += 8)
    out[(size_t)(c0 + ty + i) * R + r0 + tx] = f2bf(tile[tx][ty + i]);
}

// bf16 per-head transpose: vw [bh][1024 s][64 d] -> vt [bh][64 d][1024 s]
__global__ __launch_bounds__(256) void transpose_v(const unsigned short* __restrict__ vw,
                                                   unsigned short* __restrict__ vt) {
  __shared__ unsigned short tile[32][33];
  int bh = blockIdx.z;
  int d0 = blockIdx.x * 32, s0 = blockIdx.y * 32;
  const unsigned short* in = vw + (size_t)bh * NS * HD;
  unsigned short* out = vt + (size_t)bh * HD * NS;
  int tx = threadIdx.x & 31, ty = threadIdx.x >> 5;  // 32 x 8
#pragma unroll
  for (int i = 0; i < 32; i += 8)
    tile[ty + i][tx] = in[(size_t)(s0 + ty + i) * HD + d0 + tx];
  __syncthreads();
#pragma unroll
  for (int i = 0; i < 32; i += 8)
    out[(size_t)(d0 + ty + i) * NS + s0 + tx] = tile[tx][ty + i];
}

// ---------------- GEMM mainloop: 2-phase double-buffered prefetch (T3-minimal) ----------------
// A:[M][K] bf16, Bt:[N][K] bf16. 128x128 tile, BK=64, 4 waves (2x2).
// LDS: 2 buffers per operand. Loads for tile t+1 issued BEFORE compute of tile t;
// the single __syncthreads per tile provides the vmcnt(0)+lgkmcnt(0) drain.

__device__ __forceinline__ void gemm_mainloop(const unsigned short* __restrict__ A,
                                              const unsigned short* __restrict__ Bt,
                                              int K, int m0, int n0,
                                              unsigned short* As, unsigned short* Bs,
                                              f32x4 (&acc)[4][4]) {
  int tid = threadIdx.x;
  int lane = tid & 63, wid = tid >> 6;
  int wr = wid >> 1, wc = wid & 1;
  int ll = lane & 15, lh = lane >> 4;

  // staging: wave w owns rows [w*32, w*32+32); each gload16 covers 8 rows (64 lanes x 16B)
  int lrow = wid * 32 + (lane >> 3);
  int lcol = (lane & 7) * 8;
  const unsigned short* asrc = A + (size_t)(m0 + lrow) * K + lcol;
  const unsigned short* bsrc = Bt + (size_t)(n0 + lrow) * K + lcol;
  unsigned short* adst = As + wid * 2048;  // wave-uniform base within buffer
  unsigned short* bdst = Bs + wid * 2048;

  // prologue: stage K-tile 0 into buffer 0
#pragma unroll
  for (int i = 0; i < 4; i++) {
    gload16(adst + i * 512, asrc + (size_t)i * 8 * K);
    gload16(bdst + i * 512, bsrc + (size_t)i * 8 * K);
  }
  __syncthreads();

  const int nt = K / 64;
  for (int t = 0; t < nt; ++t) {
    const unsigned short* Ab = As + (t & 1) * 8192;
    const unsigned short* Bb = Bs + (t & 1) * 8192;

    // prefetch tile t+1 into the other buffer; stays in flight during MFMA
    if (t + 1 < nt) {
      int nx = (t + 1) & 1;
#pragma unroll
      for (int i = 0; i < 4; i++) {
        gload16(As + nx * 8192 + wid * 2048 + i * 512,
                asrc + (size_t)i * 8 * K + (size_t)(t + 1) * 64);
        gload16(Bs + nx * 8192 + wid * 2048 + i * 512,
                bsrc + (size_t)i * 8 * K + (size_t)(t + 1) * 64);
      }
    }

#pragma unroll
    for (int c = 0; c < 2; c++) {
      bf16x8 af[4], bg[4];
#pragma unroll
      for (int m = 0; m < 4; m++)
        af[m] = ld8(&Ab[(wr * 64 + m * 16 + ll) * 64 + c * 32 + lh * 8]);
#pragma unroll
      for (int n = 0; n < 4; n++)
        bg[n] = ld8(&Bb[(wc * 64 + n * 16 + ll) * 64 + c * 32 + lh * 8]);
#pragma unroll
      for (int m = 0; m < 4; m++)
#pragma unroll
        for (int n = 0; n < 4; n++) acc[m][n] = mfma16(af[m], bg[n], acc[m][n]);
    }
    __syncthreads();  // drain: tile t+1 staged, tile t reads complete
  }
}

// ---------------- QKV GEMM ----------------

__global__ __launch_bounds__(256) void qkv_gemm(const unsigned short* __restrict__ xbf,
                                                const unsigned short* __restrict__ WT,
                                                const float* __restrict__ bias,
                                                unsigned short* __restrict__ qw,
                                                unsigned short* __restrict__ kw,
                                                unsigned short* __restrict__ vw) {
  __shared__ __align__(16) unsigned short As[2 * 128 * 64];
  __shared__ __align__(16) unsigned short Bs[2 * 128 * 64];
  int m0 = blockIdx.y * 128, n0 = blockIdx.x * 128;
  f32x4 acc[4][4];
#pragma unroll
  for (int m = 0; m < 4; m++)
#pragma unroll
    for (int n = 0; n < 4; n++) acc[m][n] = (f32x4){0.f, 0.f, 0.f, 0.f};

  gemm_mainloop(xbf, WT, ND, m0, n0, As, Bs, acc);

  int tid = threadIdx.x, lane = tid & 63, wid = tid >> 6;
  int wr = wid >> 1, wc = wid & 1;
  int ll = lane & 15, lh = lane >> 4;
#pragma unroll
  for (int nf = 0; nf < 4; nf++) {
    int col = n0 + wc * 64 + nf * 16 + ll;
    float bv = bias[col];
    int which = col / ND;
    int w2 = col - which * ND;
    int h = w2 >> 6, d = w2 & 63;
#pragma unroll
    for (int mf = 0; mf < 4; mf++) {
#pragma unroll
      for (int r = 0; r < 4; r++) {
        int m = m0 + wr * 64 + mf * 16 + lh * 4 + r;
        int b = m >> 10, s = m & 1023;
        float v = acc[mf][nf][r] + bv;
        size_t idx = (((size_t)b * NH + h) * NS + s) * HD + d;
        if (which == 0)
          qw[idx] = f2bf(v * 0.125f);
        else if (which == 1)
          kw[idx] = f2bf(v);
        else
          vw[idx] = f2bf(v);
      }
    }
  }
}

// ---------------- flash attention: QBLK=128, 8 waves, swapped QK^T ----------------

#define LP 88  // LDS row stride (shorts): 176B, 16B-aligned

__global__ __launch_bounds__(512) void attn_kernel(const unsigned short* __restrict__ qw,
                                                   const unsigned short* __restrict__ kw,
                                                   const unsigned short* __restrict__ vt,
                                                   unsigned short* __restrict__ attn_out) {
  int qt = (int)gridDim.x - 1 - (int)blockIdx.x;  // heavy tiles dispatch first
  int h = blockIdx.y, b = blockIdx.z;
  __shared__ __align__(16) unsigned short Ks[64 * LP];
  __shared__ __align__(16) unsigned short Vs[64 * LP];
  __shared__ __align__(16) unsigned short Ps[8][16 * LP];

  int tid = threadIdx.x, lane = tid & 63, wid = tid >> 6;
  int ll = lane & 15, lh = lane >> 4;
  int q0 = qt * 128;
  const size_t bh = ((size_t)b * NH + h) * NS * HD;

  int qrow = q0 + wid * 16 + ll;
  bf16x8 qf0 = ld8(&qw[bh + (size_t)qrow * HD + lh * 8]);
  bf16x8 qf1 = ld8(&qw[bh + (size_t)qrow * HD + 32 + lh * 8]);

  f32x4 o[4];
#pragma unroll
  for (int n = 0; n < 4; n++) o[n] = (f32x4){0.f, 0.f, 0.f, 0.f};
  float m_r = -1e30f, l_r = 0.f;

  int srow = tid >> 3, sc = (tid & 7) * 8;
  const unsigned short* ksrc = kw + bh + (size_t)srow * HD + sc;
  const unsigned short* vsrc = vt + bh + (size_t)srow * NS + sc;
  unsigned short* kdst = &Ks[srow * LP + sc];
  unsigned short* vdst = &Vs[srow * LP + sc];

  int qmaxw = q0 + wid * 16 + 15;
  int jend = q0 + 128;
  unsigned short* pw = &Ps[wid][ll * LP];

  for (int j0 = 0; j0 < jend; j0 += 64) {
    __syncthreads();
    *(s16x8*)kdst = *(const s16x8*)(ksrc + (size_t)j0 * HD);
    *(s16x8*)vdst = *(const s16x8*)(vsrc + j0);
    __syncthreads();

    if (j0 <= qmaxw) {
      f32x4 sa[4];
#pragma unroll
      for (int n = 0; n < 4; n++) {
        bf16x8 kf0 = ld8(&Ks[(n * 16 + ll) * LP + lh * 8]);
        bf16x8 kf1 = ld8(&Ks[(n * 16 + ll) * LP + 32 + lh * 8]);
        sa[n] = mfma16(kf0, qf0, (f32x4){0.f, 0.f, 0.f, 0.f});
        sa[n] = mfma16(kf1, qf1, sa[n]);
      }

      int qme = q0 + wid * 16 + ll;
      if (j0 + 63 > q0 + wid * 16) {
#pragma unroll
        for (int n = 0; n < 4; n++)
#pragma unroll
          for (int r = 0; r < 4; r++)
            if (j0 + n * 16 + lh * 4 + r > qme) sa[n][r] = -1e30f;
      }

      float t0 = fmaxf(fmaxf(sa[0][0], sa[0][1]), fmaxf(sa[0][2], sa[0][3]));
      float t1 = fmaxf(fmaxf(sa[1][0], sa[1][1]), fmaxf(sa[1][2], sa[1][3]));
      float t2 = fmaxf(fmaxf(sa[2][0], sa[2][1]), fmaxf(sa[2][2], sa[2][3]));
      float t3 = fmaxf(fmaxf(sa[3][0], sa[3][1]), fmaxf(sa[3][2], sa[3][3]));
      float tmax = fmaxf(fmaxf(t0, t1), fmaxf(t2, t3));
      tmax = fmaxf(tmax, __shfl_xor(tmax, 16));
      tmax = fmaxf(tmax, __shfl_xor(tmax, 32));
      float mnew = fmaxf(m_r, tmax);
      float alpha = __expf(m_r - mnew);
      m_r = mnew;

      float p[4][4];
      float ssum = 0.f;
#pragma unroll
      for (int n = 0; n < 4; n++)
#pragma unroll
        for (int r = 0; r < 4; r++) {
          p[n][r] = __expf(sa[n][r] - mnew);
          ssum += p[n][r];
        }
      ssum += __shfl_xor(ssum, 16);
      ssum += __shfl_xor(ssum, 32);
      l_r = alpha * l_r + ssum;

      float ab0 = __shfl(alpha, lh * 4 + 0);
      float ab1 = __shfl(alpha, lh * 4 + 1);
      float ab2 = __shfl(alpha, lh * 4 + 2);
      float ab3 = __shfl(alpha, lh * 4 + 3);
#pragma unroll
      for (int n2 = 0; n2 < 4; n2++) {
        o[n2][0] *= ab0; o[n2][1] *= ab1; o[n2][2] *= ab2; o[n2][3] *= ab3;
      }

#pragma unroll
      for (int n = 0; n < 4; n++) {
        s16x4 pk;
        pk[0] = (short)f2bf(p[n][0]);
        pk[1] = (short)f2bf(p[n][1]);
        pk[2] = (short)f2bf(p[n][2]);
        pk[3] = (short)f2bf(p[n][3]);
        *(s16x4*)&pw[n * 16 + lh * 4] = pk;
      }

#pragma unroll
      for (int c = 0; c < 2; c++) {
        bf16x8 pf = ld8(&pw[c * 32 + lh * 8]);
#pragma unroll
        for (int n2 = 0; n2 < 4; n2++) {
          bf16x8 vf = ld8(&Vs[(n2 * 16 + ll) * LP + c * 32 + lh * 8]);
          o[n2] = mfma16(pf, vf, o[n2]);
        }
      }
    }
  }

  float lrec = 1.0f / l_r;
  float lb0 = __shfl(lrec, lh * 4 + 0);
  float lb1 = __shfl(lrec, lh * 4 + 1);
  float lb2 = __shfl(lrec, lh * 4 + 2);
  float lb3 = __shfl(lrec, lh * 4 + 3);
#pragma unroll
  for (int n2 = 0; n2 < 4; n2++) {
    int d = n2 * 16 + ll;
    int qb = q0 + wid * 16 + lh * 4;
    attn_out[((size_t)b * NS + qb + 0) * ND + h * HD + d] = f2bf(o[n2][0] * lb0);
    attn_out[((size_t)b * NS + qb + 1) * ND + h * HD + d] = f2bf(o[n2][1] * lb1);
    attn_out[((size_t)b * NS + qb + 2) * ND + h * HD + d] = f2bf(o[n2][2] * lb2);
    attn_out[((size_t)b * NS + qb + 3) * ND + h * HD + d] = f2bf(o[n2][3] * lb3);
  }
}

// ---------------- proj GEMM ----------------

__global__ __launch_bounds__(256) void proj_gemm(const unsigned short* __restrict__ abf,
                                                 const unsigned short* __restrict__ WT,
                                                 const float* __restrict__ bias,
                                                 float* __restrict__ out) {
  __shared__ __align__(16) unsigned short As[2 * 128 * 64];
  __shared__ __align__(16) unsigned short Bs[2 * 128 * 64];
  int m0 = blockIdx.y * 128, n0 = blockIdx.x * 128;
  f32x4 acc[4][4];
#pragma unroll
  for (int m = 0; m < 4; m++)
#pragma unroll
    for (int n = 0; n < 4; n++) acc[m][n] = (f32x4){0.f, 0.f, 0.f, 0.f};

  gemm_mainloop(abf, WT, ND, m0, n0, As, Bs, acc);

  int tid = threadIdx.x, lane = tid & 63, wid = tid >> 6;
  int wr = wid >> 1, wc = wid & 1;
  int ll = lane & 15, lh = lane >> 4;
#pragma unroll
  for (int nf = 0; nf < 4; nf++) {
    int col = n0 + wc * 64 + nf * 16 + ll;
    float bv = bias[col];
#pragma unroll
    for (int mf = 0; mf < 4; mf++) {
#pragma unroll
      for (int r = 0; r < 4; r++) {
        int m = m0 + wr * 64 + mf * 16 + lh * 4 + r;
        out[(size_t)m * ND + col] = acc[mf][nf][r] + bv;
      }
    }
  }
}

// ---------------- launch ----------------

extern "C" void kernel_launch(void* const* d_in, const int* in_sizes, int n_in,
                              void* d_out, int out_size, void* d_ws, size_t ws_size,
                              hipStream_t stream) {
  const float* x = (const float*)d_in[0];
  const float* Wqkv = (const float*)d_in[1];
  const float* bqkv = (const float*)d_in[2];
  const float* Wproj = (const float*)d_in[3];
  const float* bproj = (const float*)d_in[4];
  float* out = (float*)d_out;

  char* ws = (char*)d_ws;
  const size_t SZ_X = (size_t)NB * NS * ND * 2;
  const size_t SZ_WQKV = (size_t)ND * 3 * ND * 2;
  const size_t SZ_WPROJ = (size_t)ND * ND * 2;
  const size_t SZ_HEAD = (size_t)NB * NH * NS * HD;  // elements

  unsigned short* xbf = (unsigned short*)(ws);
  unsigned short* wqkvT = (unsigned short*)(ws + SZ_X);
  unsigned short* wprojT = (unsigned short*)(ws + SZ_X + SZ_WQKV);
  unsigned short* qw = (unsigned short*)(ws + SZ_X + SZ_WQKV + SZ_WPROJ);
  unsigned short* kw = qw + SZ_HEAD;
  unsigned short* vw = kw + SZ_HEAD;
  unsigned short* attn = vw + SZ_HEAD;
  unsigned short* vtb = xbf;  // reuse x's slot: x consumed by qkv_gemm before transpose_v

  (void)in_sizes; (void)n_in; (void)out_size; (void)ws_size;

  cvt_f32_bf16<<<(NB * NS * ND) / 1024, 256, 0, stream>>>(x, xbf);
  transpose_cvt<<<dim3(3 * ND / 32, ND / 32), 256, 0, stream>>>(Wqkv, wqkvT, ND, 3 * ND);
  transpose_cvt<<<dim3(ND / 32, ND / 32), 256, 0, stream>>>(Wproj, wprojT, ND, ND);

  qkv_gemm<<<dim3(3 * ND / 128, NB * NS / 128), 256, 0, stream>>>(xbf, wqkvT, bqkv, qw, kw, vw);

  transpose_v<<<dim3(HD / 32, NS / 32, NB * NH), 256, 0, stream>>>(vw, vtb);

  attn_kernel<<<dim3(NS / 128, NH, NB), 512, 0, stream>>>(qw, kw, vtb, attn);

  proj_gemm<<<dim3(ND / 128, NB * NS / 128), 256, 0, stream>>>(attn, wprojT, bproj, out);
}

// Round 5
// 156.874 us; speedup vs baseline: 1.2085x; 1.2085x over previous
//
#include <hip/hip_runtime.h>
#include <cstddef>

typedef float f32x4 __attribute__((ext_vector_type(4)));
typedef short s16x4 __attribute__((ext_vector_type(4)));
typedef short s16x8 __attribute__((ext_vector_type(8)));
typedef __bf16 bf16x8 __attribute__((ext_vector_type(8)));

#define NB 8
#define NS 1024
#define ND 768
#define NH 12
#define HD 64

#define SLOT_A 16384  // shorts: 256 rows x 64 cols
#define SLOT_B 8192   // shorts: 128 rows x 64 cols
#define GEMM_LDS_BYTES ((3 * SLOT_A + 3 * SLOT_B) * 2)  // 147456

__device__ __forceinline__ unsigned short f2bf(float f) {
  unsigned u = __builtin_bit_cast(unsigned, f);
  u += 0x7fffu + ((u >> 16) & 1u);
  return (unsigned short)(u >> 16);
}

__device__ __forceinline__ f32x4 mfma16(bf16x8 a, bf16x8 b, f32x4 c) {
  return __builtin_amdgcn_mfma_f32_16x16x32_bf16(a, b, c, 0, 0, 0);
}

__device__ __forceinline__ bf16x8 ld8(const unsigned short* p) {
  return *reinterpret_cast<const bf16x8*>(p);
}

// async global->LDS, 16B/lane, wave-uniform LDS base + lane*16
__device__ __forceinline__ void gload16(unsigned short* lds_dst, const unsigned short* gsrc) {
  __builtin_amdgcn_global_load_lds(
      (const __attribute__((address_space(1))) unsigned int*)gsrc,
      (__attribute__((address_space(3))) unsigned int*)lds_dst, 16, 0, 0);
}

// ---------------- pack kernels ----------------

__global__ __launch_bounds__(256) void cvt_f32_bf16(const float* __restrict__ in,
                                                    unsigned short* __restrict__ out) {
  int i = (blockIdx.x * 256 + threadIdx.x) * 4;
  float4 v = *reinterpret_cast<const float4*>(in + i);
  ushort4 o;
  o.x = f2bf(v.x); o.y = f2bf(v.y); o.z = f2bf(v.z); o.w = f2bf(v.w);
  *reinterpret_cast<ushort4*>(out + i) = o;
}

// in: fp32 [R][C] row-major  ->  out: bf16 [C][R]
__global__ __launch_bounds__(256) void transpose_cvt(const float* __restrict__ in,
                                                     unsigned short* __restrict__ out,
                                                     int R, int C) {
  __shared__ float tile[32][33];
  int c0 = blockIdx.x * 32, r0 = blockIdx.y * 32;
  int tx = threadIdx.x & 31, ty = threadIdx.x >> 5;  // 32 x 8
#pragma unroll
  for (int i = 0; i < 32; i += 8)
    tile[ty + i][tx] = in[(size_t)(r0 + ty + i) * C + c0 + tx];
  __syncthreads();
#pragma unroll
  for (int i = 0; i < 32; i += 8)
    out[(size_t)(c0 + ty + i) * R + r0 + tx] = f2bf(tile[tx][ty + i]);
}

// bf16 per-head transpose: vw [bh][1024 s][64 d] -> vt [bh][64 d][1024 s]
__global__ __launch_bounds__(256) void transpose_v(const unsigned short* __restrict__ vw,
                                                   unsigned short* __restrict__ vt) {
  __shared__ unsigned short tile[32][33];
  int bh = blockIdx.z;
  int d0 = blockIdx.x * 32, s0 = blockIdx.y * 32;
  const unsigned short* in = vw + (size_t)bh * NS * HD;
  unsigned short* out = vt + (size_t)bh * HD * NS;
  int tx = threadIdx.x & 31, ty = threadIdx.x >> 5;  // 32 x 8
#pragma unroll
  for (int i = 0; i < 32; i += 8)
    tile[ty + i][tx] = in[(size_t)(s0 + ty + i) * HD + d0 + tx];
  __syncthreads();
#pragma unroll
  for (int i = 0; i < 32; i += 8)
    out[(size_t)(d0 + ty + i) * NS + s0 + tx] = tile[tx][ty + i];
}

// ---------------- GEMM mainloop: 256x128 tile, 8 waves, BK=64 ----------------
// 3-slot LDS rotation, depth-2 prefetch with counted vmcnt (never drain-0 in
// steady state), T2 XOR-swizzle: logical (row, col16) stored at byte
// row*128 + (col16 ^ (row&7))*16. LDS dest stays linear (global_load_lds rule);
// the swizzle is applied to the per-lane GLOBAL source col and to ds_read addrs.
// Race audit: iter t stages slot (t+2)%3 (last read at t-1, pre-barrier);
// reads slot t%3 (staged at t-2; end-of-(t-1) vmcnt guarantees landed).

__device__ __forceinline__ void stage_tile(const unsigned short* asrc, const unsigned short* bsrc,
                                           unsigned short* As, unsigned short* Bs,
                                           int slot, int wid, int t, int K) {
  unsigned short* ad = As + slot * SLOT_A + wid * 2048;  // wave-uniform
  unsigned short* bd = Bs + slot * SLOT_B + wid * 1024;
  const unsigned short* ag = asrc + (size_t)t * 64;
  const unsigned short* bg = bsrc + (size_t)t * 64;
#pragma unroll
  for (int i = 0; i < 4; i++) gload16(ad + i * 512, ag + (size_t)i * 8 * K);
#pragma unroll
  for (int i = 0; i < 2; i++) gload16(bd + i * 512, bg + (size_t)i * 8 * K);
}

__device__ __forceinline__ void gemm_mainloop(const unsigned short* __restrict__ A,
                                              const unsigned short* __restrict__ Bt,
                                              int K, int m0, int n0,
                                              unsigned short* As, unsigned short* Bs,
                                              f32x4 (&acc)[4][4]) {
  int tid = threadIdx.x;
  int lane = tid & 63, wid = tid >> 6;
  int wr = wid >> 1, wc = wid & 1;  // 4M x 2N waves; per-wave 64x64 out
  int ll = lane & 15, lh = lane >> 4;
  int swz = ((lane & 7) ^ ((lane >> 3) & 7)) * 8;  // inverse-swizzled source col

  const unsigned short* asrc = A + (size_t)(m0 + wid * 32 + (lane >> 3)) * K + swz;
  const unsigned short* bsrc = Bt + (size_t)(n0 + wid * 16 + (lane >> 3)) * K + swz;

  const int nt = K / 64;  // >= 3

  stage_tile(asrc, bsrc, As, Bs, 0, wid, 0, K);
  stage_tile(asrc, bsrc, As, Bs, 1, wid, 1, K);
  asm volatile("s_waitcnt vmcnt(6)" ::: "memory");  // tile 0 landed; tile 1 in flight
  __builtin_amdgcn_s_barrier();
  asm volatile("" ::: "memory");

  int slot = 0;
  for (int t = 0; t < nt; ++t) {
    if (t + 2 < nt) {
      int s2 = slot + 2; if (s2 >= 3) s2 -= 3;
      stage_tile(asrc, bsrc, As, Bs, s2, wid, t + 2, K);
    }
    const unsigned short* Ab = As + slot * SLOT_A;
    const unsigned short* Bb = Bs + slot * SLOT_B;

    __builtin_amdgcn_s_setprio(1);
#pragma unroll
    for (int c = 0; c < 2; c++) {
      int sc = ((c * 4 + lh) ^ (ll & 7)) << 3;  // swizzled ds_read col (shorts)
      bf16x8 af[4], bg[4];
#pragma unroll
      for (int m = 0; m < 4; m++) af[m] = ld8(&Ab[(wr * 64 + m * 16 + ll) * 64 + sc]);
#pragma unroll
      for (int n = 0; n < 4; n++) bg[n] = ld8(&Bb[(wc * 64 + n * 16 + ll) * 64 + sc]);
#pragma unroll
      for (int m = 0; m < 4; m++)
#pragma unroll
        for (int n = 0; n < 4; n++) acc[m][n] = mfma16(af[m], bg[n], acc[m][n]);
    }
    __builtin_amdgcn_s_setprio(0);

    if (t + 2 < nt) {
      asm volatile("s_waitcnt vmcnt(6)" ::: "memory");  // tile t+1 landed; t+2 flying
      __builtin_amdgcn_s_barrier();
      asm volatile("" ::: "memory");
    } else if (t + 2 == nt) {
      asm volatile("s_waitcnt vmcnt(0)" ::: "memory");  // final tile: full drain once
      __builtin_amdgcn_s_barrier();
      asm volatile("" ::: "memory");
    }
    slot++; if (slot == 3) slot = 0;
  }
}

// ---------------- QKV GEMM ----------------

__global__ __launch_bounds__(512, 1) void qkv_gemm(const unsigned short* __restrict__ xbf,
                                                   const unsigned short* __restrict__ WT,
                                                   const float* __restrict__ bias,
                                                   unsigned short* __restrict__ qw,
                                                   unsigned short* __restrict__ kw,
                                                   unsigned short* __restrict__ vw) {
  extern __shared__ __align__(16) unsigned short smem[];
  unsigned short* As = smem;
  unsigned short* Bs = smem + 3 * SLOT_A;
  int m0 = blockIdx.y * 256, n0 = blockIdx.x * 128;
  f32x4 acc[4][4];
#pragma unroll
  for (int m = 0; m < 4; m++)
#pragma unroll
    for (int n = 0; n < 4; n++) acc[m][n] = (f32x4){0.f, 0.f, 0.f, 0.f};

  gemm_mainloop(xbf, WT, ND, m0, n0, As, Bs, acc);

  int tid = threadIdx.x, lane = tid & 63, wid = tid >> 6;
  int wr = wid >> 1, wc = wid & 1;
  int ll = lane & 15, lh = lane >> 4;
#pragma unroll
  for (int nf = 0; nf < 4; nf++) {
    int col = n0 + wc * 64 + nf * 16 + ll;
    float bv = bias[col];
    int which = col / ND;
    int w2 = col - which * ND;
    int h = w2 >> 6, d = w2 & 63;
#pragma unroll
    for (int mf = 0; mf < 4; mf++) {
#pragma unroll
      for (int r = 0; r < 4; r++) {
        int m = m0 + wr * 64 + mf * 16 + lh * 4 + r;
        int b = m >> 10, s = m & 1023;
        float v = acc[mf][nf][r] + bv;
        size_t idx = (((size_t)b * NH + h) * NS + s) * HD + d;
        if (which == 0)
          qw[idx] = f2bf(v * 0.125f);
        else if (which == 1)
          kw[idx] = f2bf(v);
        else
          vw[idx] = f2bf(v);
      }
    }
  }
}

// ---------------- flash attention: QBLK=128, 8 waves, swapped QK^T ----------------

#define LP 88  // LDS row stride (shorts): 176B, 16B-aligned

__global__ __launch_bounds__(512) void attn_kernel(const unsigned short* __restrict__ qw,
                                                   const unsigned short* __restrict__ kw,
                                                   const unsigned short* __restrict__ vt,
                                                   unsigned short* __restrict__ attn_out) {
  int qt = (int)gridDim.x - 1 - (int)blockIdx.x;  // heavy tiles dispatch first
  int h = blockIdx.y, b = blockIdx.z;
  __shared__ __align__(16) unsigned short Ks[64 * LP];
  __shared__ __align__(16) unsigned short Vs[64 * LP];
  __shared__ __align__(16) unsigned short Ps[8][16 * LP];

  int tid = threadIdx.x, lane = tid & 63, wid = tid >> 6;
  int ll = lane & 15, lh = lane >> 4;
  int q0 = qt * 128;
  const size_t bh = ((size_t)b * NH + h) * NS * HD;

  int qrow = q0 + wid * 16 + ll;
  bf16x8 qf0 = ld8(&qw[bh + (size_t)qrow * HD + lh * 8]);
  bf16x8 qf1 = ld8(&qw[bh + (size_t)qrow * HD + 32 + lh * 8]);

  f32x4 o[4];
#pragma unroll
  for (int n = 0; n < 4; n++) o[n] = (f32x4){0.f, 0.f, 0.f, 0.f};
  float m_r = -1e30f, l_r = 0.f;

  int srow = tid >> 3, sc = (tid & 7) * 8;
  const unsigned short* ksrc = kw + bh + (size_t)srow * HD + sc;
  const unsigned short* vsrc = vt + bh + (size_t)srow * NS + sc;
  unsigned short* kdst = &Ks[srow * LP + sc];
  unsigned short* vdst = &Vs[srow * LP + sc];

  int qmaxw = q0 + wid * 16 + 15;
  int jend = q0 + 128;
  unsigned short* pw = &Ps[wid][ll * LP];

  for (int j0 = 0; j0 < jend; j0 += 64) {
    __syncthreads();
    *(s16x8*)kdst = *(const s16x8*)(ksrc + (size_t)j0 * HD);
    *(s16x8*)vdst = *(const s16x8*)(vsrc + j0);
    __syncthreads();

    if (j0 <= qmaxw) {
      f32x4 sa[4];
#pragma unroll
      for (int n = 0; n < 4; n++) {
        bf16x8 kf0 = ld8(&Ks[(n * 16 + ll) * LP + lh * 8]);
        bf16x8 kf1 = ld8(&Ks[(n * 16 + ll) * LP + 32 + lh * 8]);
        sa[n] = mfma16(kf0, qf0, (f32x4){0.f, 0.f, 0.f, 0.f});
        sa[n] = mfma16(kf1, qf1, sa[n]);
      }

      int qme = q0 + wid * 16 + ll;
      if (j0 + 63 > q0 + wid * 16) {
#pragma unroll
        for (int n = 0; n < 4; n++)
#pragma unroll
          for (int r = 0; r < 4; r++)
            if (j0 + n * 16 + lh * 4 + r > qme) sa[n][r] = -1e30f;
      }

      float t0 = fmaxf(fmaxf(sa[0][0], sa[0][1]), fmaxf(sa[0][2], sa[0][3]));
      float t1 = fmaxf(fmaxf(sa[1][0], sa[1][1]), fmaxf(sa[1][2], sa[1][3]));
      float t2 = fmaxf(fmaxf(sa[2][0], sa[2][1]), fmaxf(sa[2][2], sa[2][3]));
      float t3 = fmaxf(fmaxf(sa[3][0], sa[3][1]), fmaxf(sa[3][2], sa[3][3]));
      float tmax = fmaxf(fmaxf(t0, t1), fmaxf(t2, t3));
      tmax = fmaxf(tmax, __shfl_xor(tmax, 16));
      tmax = fmaxf(tmax, __shfl_xor(tmax, 32));
      float mnew = fmaxf(m_r, tmax);
      float alpha = __expf(m_r - mnew);
      m_r = mnew;

      float p[4][4];
      float ssum = 0.f;
#pragma unroll
      for (int n = 0; n < 4; n++)
#pragma unroll
        for (int r = 0; r < 4; r++) {
          p[n][r] = __expf(sa[n][r] - mnew);
          ssum += p[n][r];
        }
      ssum += __shfl_xor(ssum, 16);
      ssum += __shfl_xor(ssum, 32);
      l_r = alpha * l_r + ssum;

      float ab0 = __shfl(alpha, lh * 4 + 0);
      float ab1 = __shfl(alpha, lh * 4 + 1);
      float ab2 = __shfl(alpha, lh * 4 + 2);
      float ab3 = __shfl(alpha, lh * 4 + 3);
#pragma unroll
      for (int n2 = 0; n2 < 4; n2++) {
        o[n2][0] *= ab0; o[n2][1] *= ab1; o[n2][2] *= ab2; o[n2][3] *= ab3;
      }

#pragma unroll
      for (int n = 0; n < 4; n++) {
        s16x4 pk;
        pk[0] = (short)f2bf(p[n][0]);
        pk[1] = (short)f2bf(p[n][1]);
        pk[2] = (short)f2bf(p[n][2]);
        pk[3] = (short)f2bf(p[n][3]);
        *(s16x4*)&pw[n * 16 + lh * 4] = pk;
      }

#pragma unroll
      for (int c = 0; c < 2; c++) {
        bf16x8 pf = ld8(&pw[c * 32 + lh * 8]);
#pragma unroll
        for (int n2 = 0; n2 < 4; n2++) {
          bf16x8 vf = ld8(&Vs[(n2 * 16 + ll) * LP + c * 32 + lh * 8]);
          o[n2] = mfma16(pf, vf, o[n2]);
        }
      }
    }
  }

  float lrec = 1.0f / l_r;
  float lb0 = __shfl(lrec, lh * 4 + 0);
  float lb1 = __shfl(lrec, lh * 4 + 1);
  float lb2 = __shfl(lrec, lh * 4 + 2);
  float lb3 = __shfl(lrec, lh * 4 + 3);
#pragma unroll
  for (int n2 = 0; n2 < 4; n2++) {
    int d = n2 * 16 + ll;
    int qb = q0 + wid * 16 + lh * 4;
    attn_out[((size_t)b * NS + qb + 0) * ND + h * HD + d] = f2bf(o[n2][0] * lb0);
    attn_out[((size_t)b * NS + qb + 1) * ND + h * HD + d] = f2bf(o[n2][1] * lb1);
    attn_out[((size_t)b * NS + qb + 2) * ND + h * HD + d] = f2bf(o[n2][2] * lb2);
    attn_out[((size_t)b * NS + qb + 3) * ND + h * HD + d] = f2bf(o[n2][3] * lb3);
  }
}

// ---------------- proj GEMM ----------------

__global__ __launch_bounds__(512, 1) void proj_gemm(const unsigned short* __restrict__ abf,
                                                    const unsigned short* __restrict__ WT,
                                                    const float* __restrict__ bias,
                                                    float* __restrict__ out) {
  extern __shared__ __align__(16) unsigned short smem[];
  unsigned short* As = smem;
  unsigned short* Bs = smem + 3 * SLOT_A;
  int m0 = blockIdx.y * 256, n0 = blockIdx.x * 128;
  f32x4 acc[4][4];
#pragma unroll
  for (int m = 0; m < 4; m++)
#pragma unroll
    for (int n = 0; n < 4; n++) acc[m][n] = (f32x4){0.f, 0.f, 0.f, 0.f};

  gemm_mainloop(abf, WT, ND, m0, n0, As, Bs, acc);

  int tid = threadIdx.x, lane = tid & 63, wid = tid >> 6;
  int wr = wid >> 1, wc = wid & 1;
  int ll = lane & 15, lh = lane >> 4;
#pragma unroll
  for (int nf = 0; nf < 4; nf++) {
    int col = n0 + wc * 64 + nf * 16 + ll;
    float bv = bias[col];
#pragma unroll
    for (int mf = 0; mf < 4; mf++) {
#pragma unroll
      for (int r = 0; r < 4; r++) {
        int m = m0 + wr * 64 + mf * 16 + lh * 4 + r;
        out[(size_t)m * ND + col] = acc[mf][nf][r] + bv;
      }
    }
  }
}

// ---------------- launch ----------------

extern "C" void kernel_launch(void* const* d_in, const int* in_sizes, int n_in,
                              void* d_out, int out_size, void* d_ws, size_t ws_size,
                              hipStream_t stream) {
  const float* x = (const float*)d_in[0];
  const float* Wqkv = (const float*)d_in[1];
  const float* bqkv = (const float*)d_in[2];
  const float* Wproj = (const float*)d_in[3];
  const float* bproj = (const float*)d_in[4];
  float* out = (float*)d_out;

  char* ws = (char*)d_ws;
  const size_t SZ_X = (size_t)NB * NS * ND * 2;
  const size_t SZ_WQKV = (size_t)ND * 3 * ND * 2;
  const size_t SZ_WPROJ = (size_t)ND * ND * 2;
  const size_t SZ_HEAD = (size_t)NB * NH * NS * HD;  // elements

  unsigned short* xbf = (unsigned short*)(ws);
  unsigned short* wqkvT = (unsigned short*)(ws + SZ_X);
  unsigned short* wprojT = (unsigned short*)(ws + SZ_X + SZ_WQKV);
  unsigned short* qw = (unsigned short*)(ws + SZ_X + SZ_WQKV + SZ_WPROJ);
  unsigned short* kw = qw + SZ_HEAD;
  unsigned short* vw = kw + SZ_HEAD;
  unsigned short* attn = vw + SZ_HEAD;
  unsigned short* vtb = xbf;  // reuse x's slot: x consumed by qkv_gemm before transpose_v

  (void)in_sizes; (void)n_in; (void)out_size; (void)ws_size;

  // opt-in for >64KB dynamic LDS (idempotent; not a stream op, capture-safe)
  hipFuncSetAttribute(reinterpret_cast<const void*>(qkv_gemm),
                      hipFuncAttributeMaxDynamicSharedMemorySize, GEMM_LDS_BYTES);
  hipFuncSetAttribute(reinterpret_cast<const void*>(proj_gemm),
                      hipFuncAttributeMaxDynamicSharedMemorySize, GEMM_LDS_BYTES);

  cvt_f32_bf16<<<(NB * NS * ND) / 1024, 256, 0, stream>>>(x, xbf);
  transpose_cvt<<<dim3(3 * ND / 32, ND / 32), 256, 0, stream>>>(Wqkv, wqkvT, ND, 3 * ND);
  transpose_cvt<<<dim3(ND / 32, ND / 32), 256, 0, stream>>>(Wproj, wprojT, ND, ND);

  qkv_gemm<<<dim3(3 * ND / 128, NB * NS / 256), 512, GEMM_LDS_BYTES, stream>>>(
      xbf, wqkvT, bqkv, qw, kw, vw);

  transpose_v<<<dim3(HD / 32, NS / 32, NB * NH), 256, 0, stream>>>(vw, vtb);

  attn_kernel<<<dim3(NS / 128, NH, NB), 512, 0, stream>>>(qw, kw, vtb, attn);

  proj_gemm<<<dim3(ND / 128, NB * NS / 256), 512, GEMM_LDS_BYTES, stream>>>(
      attn, wprojT, bproj, out);
}